// Round 1
// baseline (260.504 us; speedup 1.0000x reference)
//
#include <hip/hip_runtime.h>
#include <math.h>

// Problem constants (fixed by reference)
#define NB 8
#define NM 16
#define NC 3
#define NH 128
#define NW 128
#define NG (NH * NW)            // 16384 spatial elems per image
#define NGF (NH * (NW / 2 + 1)) // 8320 rfft2 elems per image
#define NKH 32                  // kept freq rows  (int(128*0.25))
#define NKW 16                  // kept freq cols  (int(65*0.25))
#define NK (NKH * NKW)          // 512 kept coefficients
#define N_PRED_IMG (NB * NM * NC) // 384
#define N_IMG (N_PRED_IMG + NB * NC) // 408

// ws layout:
//  [0, 32)                      : double acc[4]  {S_mae_p, S_pair_p, S_mae_f, S_pair_f}
//  [128, 128 + 408*512*4)       : float mag[408*512]
//  [MAG_END, +408*2048*8)       : float2 Yrow[408*128*16]
#define WS_ACC_OFF   0
#define WS_MAG_OFF   128
#define WS_MAG_BYTES (N_IMG * NK * 4)
#define WS_Y_OFF     (WS_MAG_OFF + WS_MAG_BYTES)   // 835712, 128-aligned

// ---------------------------------------------------------------------------
// Kernel 1: pointwise CRPS partial sums over (b,c,g) columns.
// N = B*C*G = 393216 threads = 1536 blocks * 256.
__global__ __launch_bounds__(256) void crps_point_kernel(
    const float* __restrict__ pred,   // (B,M,C,G) flat
    const float* __restrict__ tgt,    // (B,C,G) flat
    double* __restrict__ acc) {
  int i = blockIdx.x * 256 + threadIdx.x;          // (b, c*G+g)
  int b = i / (NC * NG);                            // / 49152
  int cg = i - b * (NC * NG);
  const float* base = pred + (size_t)b * (NM * NC * NG) + cg;
  float t = tgt[i];
  float p[NM];
#pragma unroll
  for (int m = 0; m < NM; ++m) p[m] = base[(size_t)m * (NC * NG)];
  float s1 = 0.f, s2 = 0.f;
#pragma unroll
  for (int m = 0; m < NM; ++m) s1 += fabsf(p[m] - t);
#pragma unroll
  for (int m = 0; m < NM; ++m)
#pragma unroll
    for (int j = m + 1; j < NM; ++j) s2 += fabsf(p[m] - p[j]);
  // wave64 reduce
  for (int off = 32; off > 0; off >>= 1) {
    s1 += __shfl_down(s1, off);
    s2 += __shfl_down(s2, off);
  }
  if ((threadIdx.x & 63) == 0) {
    atomicAdd(&acc[0], (double)s1);
    atomicAdd(&acc[1], (double)s2);
  }
}

// ---------------------------------------------------------------------------
// Kernel 2: row-stage partial DFT. One thread per (img, h, kw).
// Y[img][h][kw] = sum_w x[img][h][w] * exp(-2pi*i*kw*w/128)
// tasks = 408 * 128 * 16 = 835584 = 3264 blocks * 256
__global__ __launch_bounds__(256) void dft_rows_kernel(
    const float* __restrict__ pred,   // (384, 16384)
    const float* __restrict__ tgt,    // (24, 16384)
    float2* __restrict__ Y) {
  __shared__ float2 roots[NW];
  int t = threadIdx.x;
  if (t < NW) {
    float ang = -2.0f * 3.14159265358979323846f * (float)t / (float)NW;
    float s, c;
    sincosf(ang, &s, &c);
    roots[t] = make_float2(c, s);
  }
  __syncthreads();

  int i = blockIdx.x * 256 + t;
  int img = i >> 11;            // / 2048
  int rem = i & 2047;
  int h = rem >> 4;
  int kw = rem & 15;
  const float* src =
      ((img < N_PRED_IMG) ? pred + (size_t)img * NG
                          : tgt + (size_t)(img - N_PRED_IMG) * NG) +
      h * NW;
  float ax = 0.f, ay = 0.f;
  int idx = 0;
#pragma unroll 8
  for (int w = 0; w < NW; ++w) {
    float v = src[w];
    float2 r = roots[idx];
    ax = fmaf(v, r.x, ax);
    ay = fmaf(v, r.y, ay);
    idx = (idx + kw) & (NW - 1);
  }
  Y[i] = make_float2(ax, ay);
}

// ---------------------------------------------------------------------------
// Kernel 3: column-stage partial DFT + magnitude. One thread per (img, kh, kw).
// X = sum_h Y[img][h][kw] * exp(-2pi*i*kh*h/128);  mag = |X|
// tasks = 408 * 512 = 208896 = 816 blocks * 256
__global__ __launch_bounds__(256) void dft_cols_mag_kernel(
    const float2* __restrict__ Y,
    float* __restrict__ mag) {
  __shared__ float2 roots[NH];
  int t = threadIdx.x;
  if (t < NH) {
    float ang = -2.0f * 3.14159265358979323846f * (float)t / (float)NH;
    float s, c;
    sincosf(ang, &s, &c);
    roots[t] = make_float2(c, s);
  }
  __syncthreads();

  int i = blockIdx.x * 256 + t;
  int img = i >> 9;             // / 512
  int rem = i & 511;
  int kh = rem >> 4;
  int kw = rem & 15;
  const float2* ybase = Y + (size_t)img * (NH * NKW) + kw;
  float ax = 0.f, ay = 0.f;
  int idx = 0;
#pragma unroll 4
  for (int h = 0; h < NH; ++h) {
    float2 y = ybase[h * NKW];
    float2 r = roots[idx];
    ax += y.x * r.x - y.y * r.y;
    ay += y.x * r.y + y.y * r.x;
    idx = (idx + kh) & (NH - 1);
  }
  mag[i] = sqrtf(ax * ax + ay * ay);
}

// ---------------------------------------------------------------------------
// Kernel 4: frequency CRPS partial sums over (b, c, k) columns.
// N = B*C*NK = 12288 threads = 48 blocks * 256
__global__ __launch_bounds__(256) void crps_freq_kernel(
    const float* __restrict__ mag,    // (408, 512): first 384 pred, last 24 tgt
    double* __restrict__ acc) {
  int i = blockIdx.x * 256 + threadIdx.x;
  int b = i / (NC * NK);                       // / 1536
  int rem = i - b * (NC * NK);                 // c*512 + k
  const float* pb = mag + (size_t)b * (NM * NC * NK) + rem;
  float t = mag[(size_t)N_PRED_IMG * NK + (size_t)b * (NC * NK) + rem];
  float p[NM];
#pragma unroll
  for (int m = 0; m < NM; ++m) p[m] = pb[(size_t)m * (NC * NK)];
  float s1 = 0.f, s2 = 0.f;
#pragma unroll
  for (int m = 0; m < NM; ++m) s1 += fabsf(p[m] - t);
#pragma unroll
  for (int m = 0; m < NM; ++m)
#pragma unroll
    for (int j = m + 1; j < NM; ++j) s2 += fabsf(p[m] - p[j]);
  for (int off = 32; off > 0; off >>= 1) {
    s1 += __shfl_down(s1, off);
    s2 += __shfl_down(s2, off);
  }
  if ((threadIdx.x & 63) == 0) {
    atomicAdd(&acc[2], (double)s1);
    atomicAdd(&acc[3], (double)s2);
  }
}

// ---------------------------------------------------------------------------
// Kernel 5: combine the four accumulators into the scalar loss.
__global__ void finalize_kernel(const double* __restrict__ acc,
                                float* __restrict__ out) {
  if (threadIdx.x == 0 && blockIdx.x == 0) {
    const double Bd = NB, Md = NM, Cd = NC, Gd = NG, Gfd = NGF;
    const double eps = 0.05 / Md;
    double term1_p = acc[0] / (Bd * Cd * Gd * Md);
    double term2_p = (1.0 - eps) * 2.0 * acc[1] / ((Md - 1.0) * Bd * Md * Cd * Gd);
    double crps_p = term1_p - 0.5 * term2_p;
    double term1_f = acc[2] / (Bd * Cd * Gfd * Md);
    double term2_f = (1.0 - eps) * 2.0 * acc[3] / ((Md - 1.0) * Bd * Md * Cd * Gfd);
    double crps_f = term1_f - 0.5 * term2_f;
    out[0] = (float)(crps_p + 0.1 * crps_f);
  }
}

// ---------------------------------------------------------------------------
extern "C" void kernel_launch(void* const* d_in, const int* in_sizes, int n_in,
                              void* d_out, int out_size, void* d_ws, size_t ws_size,
                              hipStream_t stream) {
  (void)in_sizes; (void)n_in; (void)out_size; (void)ws_size;
  const float* tgt = (const float*)d_in[0];   // (8,3,128,128)
  const float* pred = (const float*)d_in[1];  // (8,16,3,128,128)
  float* out = (float*)d_out;

  char* ws = (char*)d_ws;
  double* acc = (double*)(ws + WS_ACC_OFF);
  float* mag = (float*)(ws + WS_MAG_OFF);
  float2* Y = (float2*)(ws + WS_Y_OFF);

  hipMemsetAsync(acc, 0, 4 * sizeof(double), stream);

  crps_point_kernel<<<(NB * NC * NG) / 256, 256, 0, stream>>>(pred, tgt, acc);
  dft_rows_kernel<<<(N_IMG * NH * NKW) / 256, 256, 0, stream>>>(pred, tgt, Y);
  dft_cols_mag_kernel<<<(N_IMG * NK) / 256, 256, 0, stream>>>(Y, mag);
  crps_freq_kernel<<<(NB * NC * NK) / 256, 256, 0, stream>>>(mag, acc);
  finalize_kernel<<<1, 64, 0, stream>>>(acc, out);
}

// Round 2
// 110.455 us; speedup vs baseline: 2.3585x; 2.3585x over previous
//
#include <hip/hip_runtime.h>
#include <math.h>

// Problem constants (fixed by reference)
#define NB 8
#define NM 16
#define NC 3
#define NH 128
#define NW 128
#define NG (NH * NW)            // 16384 spatial elems per image
#define NGF (NH * (NW / 2 + 1)) // 8320 rfft2 elems per image
#define NKH 32                  // kept freq rows  (int(128*0.25))
#define NKW 16                  // kept freq cols  (int(65*0.25))
#define NK (NKH * NKW)          // 512 kept coefficients
#define N_PRED_IMG (NB * NM * NC)    // 384
#define N_IMG (N_PRED_IMG + NB * NC) // 408

#define PT_BLOCKS 384   // point kernel blocks (4 cols/thread)
#define FQ_BLOCKS 48    // freq kernel blocks

// ws layout:
//  [0,      6144)  : double2 pp[384]   point partials {s_mae, s_pair}
//  [6144,   6912)  : double2 fp[48]    freq partials
//  [7168, +835584) : float mag[408*512]
//  [next,  +6.7MB) : float2 Yrow[408*128*16]
#define WS_PP_OFF 0
#define WS_FP_OFF (PT_BLOCKS * 16)
#define WS_MAG_OFF 7168
#define WS_MAG_BYTES (N_IMG * NK * 4)
#define WS_Y_OFF (WS_MAG_OFF + WS_MAG_BYTES)

// ---------------------------------------------------------------------------
// Kernel 1: pointwise CRPS partials. 4 columns per thread via float4.
// 393216 cols / 4 = 98304 threads = 384 blocks * 256. No global atomics.
__global__ __launch_bounds__(256) void crps_point_kernel(
    const float* __restrict__ pred,   // (B,M,C,G) flat
    const float* __restrict__ tgt,    // (B,C,G) flat
    double2* __restrict__ pp) {
  int tid = threadIdx.x;
  int i4 = (blockIdx.x * 256 + tid) * 4;            // column base
  int b = i4 / (NC * NG);                           // / 49152 (4 cols same b)
  int cg = i4 - b * (NC * NG);
  const float* base = pred + (size_t)b * (NM * NC * NG) + cg;
  float4 t = *(const float4*)&tgt[i4];
  float4 p[NM];
#pragma unroll
  for (int m = 0; m < NM; ++m)
    p[m] = *(const float4*)&base[(size_t)m * (NC * NG)];

  float s1 = 0.f, s2 = 0.f;
#pragma unroll
  for (int m = 0; m < NM; ++m) {
    s1 += fabsf(p[m].x - t.x) + fabsf(p[m].y - t.y) +
          fabsf(p[m].z - t.z) + fabsf(p[m].w - t.w);
  }
#pragma unroll
  for (int m = 0; m < NM; ++m)
#pragma unroll
    for (int j = m + 1; j < NM; ++j) {
      s2 += fabsf(p[m].x - p[j].x) + fabsf(p[m].y - p[j].y) +
            fabsf(p[m].z - p[j].z) + fabsf(p[m].w - p[j].w);
    }

  // wave64 reduce
  for (int off = 32; off > 0; off >>= 1) {
    s1 += __shfl_down(s1, off);
    s2 += __shfl_down(s2, off);
  }
  __shared__ float ls1[4], ls2[4];
  if ((tid & 63) == 0) { ls1[tid >> 6] = s1; ls2[tid >> 6] = s2; }
  __syncthreads();
  if (tid == 0) {
    double a = 0.0, c = 0.0;
#pragma unroll
    for (int w = 0; w < 4; ++w) { a += (double)ls1[w]; c += (double)ls2[w]; }
    pp[blockIdx.x] = make_double2(a, c);
  }
}

// ---------------------------------------------------------------------------
// Kernel 2: row-stage partial DFT. One thread per (img, h, kw).
// tasks = 408 * 128 * 16 = 835584 = 3264 blocks * 256
__global__ __launch_bounds__(256) void dft_rows_kernel(
    const float* __restrict__ pred,   // (384, 16384)
    const float* __restrict__ tgt,    // (24, 16384)
    float2* __restrict__ Y) {
  __shared__ float2 roots[NW];
  int t = threadIdx.x;
  if (t < NW) {
    float ang = -2.0f * 3.14159265358979323846f * (float)t / (float)NW;
    float s, c;
    sincosf(ang, &s, &c);
    roots[t] = make_float2(c, s);
  }
  __syncthreads();

  int i = blockIdx.x * 256 + t;
  int img = i >> 11;            // / 2048
  int rem = i & 2047;
  int h = rem >> 4;
  int kw = rem & 15;
  const float* src =
      ((img < N_PRED_IMG) ? pred + (size_t)img * NG
                          : tgt + (size_t)(img - N_PRED_IMG) * NG) +
      h * NW;
  float ax = 0.f, ay = 0.f;
  int idx = 0;
#pragma unroll 8
  for (int w = 0; w < NW; ++w) {
    float v = src[w];
    float2 r = roots[idx];
    ax = fmaf(v, r.x, ax);
    ay = fmaf(v, r.y, ay);
    idx = (idx + kw) & (NW - 1);
  }
  Y[i] = make_float2(ax, ay);
}

// ---------------------------------------------------------------------------
// Kernel 3: column-stage partial DFT + magnitude. One thread per (img, kh, kw).
// tasks = 408 * 512 = 208896 = 816 blocks * 256
__global__ __launch_bounds__(256) void dft_cols_mag_kernel(
    const float2* __restrict__ Y,
    float* __restrict__ mag) {
  __shared__ float2 roots[NH];
  int t = threadIdx.x;
  if (t < NH) {
    float ang = -2.0f * 3.14159265358979323846f * (float)t / (float)NH;
    float s, c;
    sincosf(ang, &s, &c);
    roots[t] = make_float2(c, s);
  }
  __syncthreads();

  int i = blockIdx.x * 256 + t;
  int img = i >> 9;             // / 512
  int rem = i & 511;
  int kh = rem >> 4;
  int kw = rem & 15;
  const float2* ybase = Y + (size_t)img * (NH * NKW) + kw;
  float ax = 0.f, ay = 0.f;
  int idx = 0;
#pragma unroll 4
  for (int h = 0; h < NH; ++h) {
    float2 y = ybase[h * NKW];
    float2 r = roots[idx];
    ax += y.x * r.x - y.y * r.y;
    ay += y.x * r.y + y.y * r.x;
    idx = (idx + kh) & (NH - 1);
  }
  mag[i] = sqrtf(ax * ax + ay * ay);
}

// ---------------------------------------------------------------------------
// Kernel 4: frequency CRPS partials. 48 blocks * 256, no global atomics.
__global__ __launch_bounds__(256) void crps_freq_kernel(
    const float* __restrict__ mag,    // (408, 512): first 384 pred, last 24 tgt
    double2* __restrict__ fp) {
  int tid = threadIdx.x;
  int i = blockIdx.x * 256 + tid;
  int b = i / (NC * NK);                       // / 1536
  int rem = i - b * (NC * NK);                 // c*512 + k
  const float* pb = mag + (size_t)b * (NM * NC * NK) + rem;
  float t = mag[(size_t)N_PRED_IMG * NK + (size_t)b * (NC * NK) + rem];
  float p[NM];
#pragma unroll
  for (int m = 0; m < NM; ++m) p[m] = pb[(size_t)m * (NC * NK)];
  float s1 = 0.f, s2 = 0.f;
#pragma unroll
  for (int m = 0; m < NM; ++m) s1 += fabsf(p[m] - t);
#pragma unroll
  for (int m = 0; m < NM; ++m)
#pragma unroll
    for (int j = m + 1; j < NM; ++j) s2 += fabsf(p[m] - p[j]);
  for (int off = 32; off > 0; off >>= 1) {
    s1 += __shfl_down(s1, off);
    s2 += __shfl_down(s2, off);
  }
  __shared__ float ls1[4], ls2[4];
  if ((tid & 63) == 0) { ls1[tid >> 6] = s1; ls2[tid >> 6] = s2; }
  __syncthreads();
  if (tid == 0) {
    double a = 0.0, c = 0.0;
#pragma unroll
    for (int w = 0; w < 4; ++w) { a += (double)ls1[w]; c += (double)ls2[w]; }
    fp[blockIdx.x] = make_double2(a, c);
  }
}

// ---------------------------------------------------------------------------
// Kernel 5: reduce partials + combine into the scalar loss. One block.
__global__ __launch_bounds__(256) void finalize_kernel(
    const double2* __restrict__ pp,   // [PT_BLOCKS]
    const double2* __restrict__ fp,   // [FQ_BLOCKS]
    float* __restrict__ out) {
  int tid = threadIdx.x;
  double s1p = 0.0, s2p = 0.0, s1f = 0.0, s2f = 0.0;
  for (int j = tid; j < PT_BLOCKS; j += 256) {
    double2 v = pp[j]; s1p += v.x; s2p += v.y;
  }
  if (tid < FQ_BLOCKS) { double2 v = fp[tid]; s1f += v.x; s2f += v.y; }
  for (int off = 32; off > 0; off >>= 1) {
    s1p += __shfl_down(s1p, off);
    s2p += __shfl_down(s2p, off);
    s1f += __shfl_down(s1f, off);
    s2f += __shfl_down(s2f, off);
  }
  __shared__ double l[4][4];
  if ((tid & 63) == 0) {
    int w = tid >> 6;
    l[w][0] = s1p; l[w][1] = s2p; l[w][2] = s1f; l[w][3] = s2f;
  }
  __syncthreads();
  if (tid == 0) {
    double a0 = 0, a1 = 0, a2 = 0, a3 = 0;
#pragma unroll
    for (int w = 0; w < 4; ++w) {
      a0 += l[w][0]; a1 += l[w][1]; a2 += l[w][2]; a3 += l[w][3];
    }
    const double Bd = NB, Md = NM, Cd = NC, Gd = NG, Gfd = NGF;
    const double eps = 0.05 / Md;
    double term1_p = a0 / (Bd * Cd * Gd * Md);
    double term2_p = (1.0 - eps) * 2.0 * a1 / ((Md - 1.0) * Bd * Md * Cd * Gd);
    double crps_p = term1_p - 0.5 * term2_p;
    double term1_f = a2 / (Bd * Cd * Gfd * Md);
    double term2_f = (1.0 - eps) * 2.0 * a3 / ((Md - 1.0) * Bd * Md * Cd * Gfd);
    double crps_f = term1_f - 0.5 * term2_f;
    out[0] = (float)(crps_p + 0.1 * crps_f);
  }
}

// ---------------------------------------------------------------------------
extern "C" void kernel_launch(void* const* d_in, const int* in_sizes, int n_in,
                              void* d_out, int out_size, void* d_ws, size_t ws_size,
                              hipStream_t stream) {
  (void)in_sizes; (void)n_in; (void)out_size; (void)ws_size;
  const float* tgt = (const float*)d_in[0];   // (8,3,128,128)
  const float* pred = (const float*)d_in[1];  // (8,16,3,128,128)
  float* out = (float*)d_out;

  char* ws = (char*)d_ws;
  double2* pp = (double2*)(ws + WS_PP_OFF);
  double2* fp = (double2*)(ws + WS_FP_OFF);
  float* mag = (float*)(ws + WS_MAG_OFF);
  float2* Y = (float2*)(ws + WS_Y_OFF);

  crps_point_kernel<<<PT_BLOCKS, 256, 0, stream>>>(pred, tgt, pp);
  dft_rows_kernel<<<(N_IMG * NH * NKW) / 256, 256, 0, stream>>>(pred, tgt, Y);
  dft_cols_mag_kernel<<<(N_IMG * NK) / 256, 256, 0, stream>>>(Y, mag);
  crps_freq_kernel<<<FQ_BLOCKS, 256, 0, stream>>>(mag, fp);
  finalize_kernel<<<1, 256, 0, stream>>>(pp, fp, out);
}

// Round 3
// 102.449 us; speedup vs baseline: 2.5428x; 1.0781x over previous
//
#include <hip/hip_runtime.h>
#include <math.h>

// Problem constants (fixed by reference)
#define NB 8
#define NM 16
#define NC 3
#define NH 128
#define NW 128
#define NG (NH * NW)            // 16384 spatial elems per image
#define NGF (NH * (NW / 2 + 1)) // 8320 rfft2 elems per image
#define NKH 32                  // kept freq rows  (int(128*0.25))
#define NKW 16                  // kept freq cols  (int(65*0.25))
#define NK (NKH * NKW)          // 512 kept coefficients
#define N_PRED_IMG (NB * NM * NC)    // 384 pred images
#define N_IMG (N_PRED_IMG + NB * NC) // 408 images incl. target

#define PT_BLOCKS 384   // point-CRPS blocks (4 cols/thread)
#define FQ_BLOCKS 48    // freq-CRPS blocks

// ws layout:
//  [0,    6144) : double2 pp[384]   point partials {s_mae, s_pair}
//  [6144, 6912) : double2 fp[48]    freq partials
//  [6912, 6916) : unsigned ctr      last-block-done counter
//  [7168, +835584) : float mag[408*512]
#define WS_PP_OFF  0
#define WS_FP_OFF  6144
#define WS_CTR_OFF 6912
#define WS_MAG_OFF 7168

#define PI_F 3.14159265358979323846f

// ---------------------------------------------------------------------------
// Kernel 1: fused pointwise-CRPS (blocks [0,384)) + per-image DFT+|.|
// (blocks [384,792), one image each, everything staged in LDS).
__global__ __launch_bounds__(256) void fused_main_kernel(
    const float* __restrict__ pred,   // (B,M,C,128,128) flat
    const float* __restrict__ tgt,    // (B,C,128,128) flat
    double2* __restrict__ pp,         // [PT_BLOCKS]
    float* __restrict__ mag,          // [408*512]
    unsigned* __restrict__ ctr) {
  __shared__ float4 xs4[32 * 33];     // 32 rows x 132 floats (pad 4) = 16896 B
  __shared__ float2 Yl[NH * NKW];     // row-DFT output, 16384 B
  __shared__ float2 roots[NH];        // e^{-2pi i k/128}, 1024 B
  __shared__ float ls1[4], ls2[4];

  const int t = threadIdx.x;
  const int blk = blockIdx.x;

  if (blk < PT_BLOCKS) {
    // ---------------- pointwise CRPS path ----------------
    if (blk == 0 && t == 0) *ctr = 0;   // arm kernel-2's last-block counter
    int i4 = (blk * 256 + t) * 4;
    int b = i4 / (NC * NG);
    int cg = i4 - b * (NC * NG);
    const float* base = pred + (size_t)b * (NM * NC * NG) + cg;
    float4 tv = *(const float4*)&tgt[i4];
    float4 p[NM];
#pragma unroll
    for (int m = 0; m < NM; ++m)
      p[m] = *(const float4*)&base[(size_t)m * (NC * NG)];

    float s1 = 0.f, s2 = 0.f;
#pragma unroll
    for (int m = 0; m < NM; ++m)
      s1 += fabsf(p[m].x - tv.x) + fabsf(p[m].y - tv.y) +
            fabsf(p[m].z - tv.z) + fabsf(p[m].w - tv.w);
#pragma unroll
    for (int m = 0; m < NM; ++m)
#pragma unroll
      for (int j = m + 1; j < NM; ++j)
        s2 += fabsf(p[m].x - p[j].x) + fabsf(p[m].y - p[j].y) +
              fabsf(p[m].z - p[j].z) + fabsf(p[m].w - p[j].w);

    for (int off = 32; off > 0; off >>= 1) {
      s1 += __shfl_down(s1, off);
      s2 += __shfl_down(s2, off);
    }
    if ((t & 63) == 0) { ls1[t >> 6] = s1; ls2[t >> 6] = s2; }
    __syncthreads();
    if (t == 0) {
      double a = 0.0, c = 0.0;
#pragma unroll
      for (int w = 0; w < 4; ++w) { a += (double)ls1[w]; c += (double)ls2[w]; }
      pp[blk] = make_double2(a, c);
    }
    return;
  }

  // ---------------- per-image DFT path ----------------
  const int img = blk - PT_BLOCKS;
  const float* src = (img < N_PRED_IMG)
                         ? pred + (size_t)img * NG
                         : tgt + (size_t)(img - N_PRED_IMG) * NG;
  const float4* src4 = (const float4*)src;

  if (t < NH) {
    float ang = -2.0f * PI_F * (float)t / (float)NH;
    float sv, cv;
    sincosf(ang, &sv, &cv);
    roots[t] = make_float2(cv, sv);
  }
  __syncthreads();

  const int kw = t & 15, r2 = t >> 4;   // row-stage task: kw, rows r2 & r2+16
  for (int c = 0; c < 4; ++c) {
    // stage 32 rows (4096 floats) coalesced
#pragma unroll
    for (int j = 0; j < 4; ++j) {
      int p = j * 256 + t;                       // float4 idx in chunk
      float4 v = src4[c * 1024 + p];
      xs4[(p >> 5) * 33 + (p & 31)] = v;
    }
    __syncthreads();

    float ax1 = 0.f, ay1 = 0.f, ax2 = 0.f, ay2 = 0.f;
    int idx = 0;                                  // (w*kw) mod 128
    const float4* rowA = &xs4[r2 * 33];
    const float4* rowB = &xs4[(r2 + 16) * 33];
#pragma unroll 4
    for (int w4 = 0; w4 < 32; ++w4) {
      float4 a = rowA[w4];
      float4 bb = rowB[w4];
      float2 rt;
      rt = roots[idx]; idx = (idx + kw) & 127;
      ax1 = fmaf(a.x, rt.x, ax1); ay1 = fmaf(a.x, rt.y, ay1);
      ax2 = fmaf(bb.x, rt.x, ax2); ay2 = fmaf(bb.x, rt.y, ay2);
      rt = roots[idx]; idx = (idx + kw) & 127;
      ax1 = fmaf(a.y, rt.x, ax1); ay1 = fmaf(a.y, rt.y, ay1);
      ax2 = fmaf(bb.y, rt.x, ax2); ay2 = fmaf(bb.y, rt.y, ay2);
      rt = roots[idx]; idx = (idx + kw) & 127;
      ax1 = fmaf(a.z, rt.x, ax1); ay1 = fmaf(a.z, rt.y, ay1);
      ax2 = fmaf(bb.z, rt.x, ax2); ay2 = fmaf(bb.z, rt.y, ay2);
      rt = roots[idx]; idx = (idx + kw) & 127;
      ax1 = fmaf(a.w, rt.x, ax1); ay1 = fmaf(a.w, rt.y, ay1);
      ax2 = fmaf(bb.w, rt.x, ax2); ay2 = fmaf(bb.w, rt.y, ay2);
    }
    Yl[(c * 32 + r2) * NKW + kw] = make_float2(ax1, ay1);
    Yl[(c * 32 + r2 + 16) * NKW + kw] = make_float2(ax2, ay2);
    __syncthreads();   // Yl complete / xs4 reusable
  }

  // column stage: X[kh][kw] = sum_h Yl[h][kw] * e^{-2pi i kh h/128}
  const int kh = t >> 3, kwb = t & 7;   // two tasks: kwb, kwb+8
  float axA = 0.f, ayA = 0.f, axB = 0.f, ayB = 0.f;
  int idx = 0;                           // (kh*h) mod 128
#pragma unroll 4
  for (int h = 0; h < NH; ++h) {
    float2 rt = roots[idx]; idx = (idx + kh) & 127;
    float2 ya = Yl[h * NKW + kwb];
    float2 yb = Yl[h * NKW + kwb + 8];
    axA += ya.x * rt.x - ya.y * rt.y; ayA += ya.x * rt.y + ya.y * rt.x;
    axB += yb.x * rt.x - yb.y * rt.y; ayB += yb.x * rt.y + yb.y * rt.x;
  }
  float* mo = mag + (size_t)img * NK;
  mo[kh * NKW + kwb] = sqrtf(axA * axA + ayA * ayA);
  mo[kh * NKW + kwb + 8] = sqrtf(axB * axB + ayB * ayB);
}

// ---------------------------------------------------------------------------
// Kernel 2: frequency CRPS partials + last-block finalize.
__global__ __launch_bounds__(256) void crps_freq_final_kernel(
    const float* __restrict__ mag,    // (408, 512): 384 pred then 24 tgt
    const double2* __restrict__ pp,   // [PT_BLOCKS]
    double2* __restrict__ fp,         // [FQ_BLOCKS]
    unsigned* __restrict__ ctr,
    float* __restrict__ out) {
  const int tid = threadIdx.x;
  int i = blockIdx.x * 256 + tid;
  int b = i / (NC * NK);
  int rem = i - b * (NC * NK);
  const float* pb = mag + (size_t)b * (NM * NC * NK) + rem;
  float t = mag[(size_t)N_PRED_IMG * NK + (size_t)b * (NC * NK) + rem];
  float p[NM];
#pragma unroll
  for (int m = 0; m < NM; ++m) p[m] = pb[(size_t)m * (NC * NK)];
  float s1 = 0.f, s2 = 0.f;
#pragma unroll
  for (int m = 0; m < NM; ++m) s1 += fabsf(p[m] - t);
#pragma unroll
  for (int m = 0; m < NM; ++m)
#pragma unroll
    for (int j = m + 1; j < NM; ++j) s2 += fabsf(p[m] - p[j]);
  for (int off = 32; off > 0; off >>= 1) {
    s1 += __shfl_down(s1, off);
    s2 += __shfl_down(s2, off);
  }
  __shared__ float ls1[4], ls2[4];
  __shared__ int sLast;
  if ((tid & 63) == 0) { ls1[tid >> 6] = s1; ls2[tid >> 6] = s2; }
  __syncthreads();
  if (tid == 0) {
    double a = 0.0, c = 0.0;
#pragma unroll
    for (int w = 0; w < 4; ++w) { a += (double)ls1[w]; c += (double)ls2[w]; }
    fp[blockIdx.x] = make_double2(a, c);
    __threadfence();                      // release fp before counter bump
    unsigned old = atomicAdd(ctr, 1u);
    sLast = (old == FQ_BLOCKS - 1);
  }
  __syncthreads();
  if (!sLast) return;
  __threadfence();                        // acquire other blocks' fp

  // ---- final reduction (one block) ----
  double s1p = 0.0, s2p = 0.0, s1f = 0.0, s2f = 0.0;
  for (int j = tid; j < PT_BLOCKS; j += 256) {
    double2 v = pp[j]; s1p += v.x; s2p += v.y;
  }
  if (tid < FQ_BLOCKS) { double2 v = fp[tid]; s1f += v.x; s2f += v.y; }
  for (int off = 32; off > 0; off >>= 1) {
    s1p += __shfl_down(s1p, off);
    s2p += __shfl_down(s2p, off);
    s1f += __shfl_down(s1f, off);
    s2f += __shfl_down(s2f, off);
  }
  __shared__ double l[4][4];
  if ((tid & 63) == 0) {
    int w = tid >> 6;
    l[w][0] = s1p; l[w][1] = s2p; l[w][2] = s1f; l[w][3] = s2f;
  }
  __syncthreads();
  if (tid == 0) {
    double a0 = 0, a1 = 0, a2 = 0, a3 = 0;
#pragma unroll
    for (int w = 0; w < 4; ++w) {
      a0 += l[w][0]; a1 += l[w][1]; a2 += l[w][2]; a3 += l[w][3];
    }
    const double Bd = NB, Md = NM, Cd = NC, Gd = NG, Gfd = NGF;
    const double eps = 0.05 / Md;
    double term1_p = a0 / (Bd * Cd * Gd * Md);
    double term2_p = (1.0 - eps) * 2.0 * a1 / ((Md - 1.0) * Bd * Md * Cd * Gd);
    double crps_p = term1_p - 0.5 * term2_p;
    double term1_f = a2 / (Bd * Cd * Gfd * Md);
    double term2_f = (1.0 - eps) * 2.0 * a3 / ((Md - 1.0) * Bd * Md * Cd * Gfd);
    double crps_f = term1_f - 0.5 * term2_f;
    out[0] = (float)(crps_p + 0.1 * crps_f);
  }
}

// ---------------------------------------------------------------------------
extern "C" void kernel_launch(void* const* d_in, const int* in_sizes, int n_in,
                              void* d_out, int out_size, void* d_ws, size_t ws_size,
                              hipStream_t stream) {
  (void)in_sizes; (void)n_in; (void)out_size; (void)ws_size;
  const float* tgt = (const float*)d_in[0];   // (8,3,128,128)
  const float* pred = (const float*)d_in[1];  // (8,16,3,128,128)
  float* out = (float*)d_out;

  char* ws = (char*)d_ws;
  double2* pp = (double2*)(ws + WS_PP_OFF);
  double2* fp = (double2*)(ws + WS_FP_OFF);
  unsigned* ctr = (unsigned*)(ws + WS_CTR_OFF);
  float* mag = (float*)(ws + WS_MAG_OFF);

  fused_main_kernel<<<PT_BLOCKS + N_IMG, 256, 0, stream>>>(pred, tgt, pp, mag, ctr);
  crps_freq_final_kernel<<<FQ_BLOCKS, 256, 0, stream>>>(mag, pp, fp, ctr, out);
}

// Round 4
// 102.309 us; speedup vs baseline: 2.5462x; 1.0014x over previous
//
#include <hip/hip_runtime.h>
#include <math.h>

// Problem constants (fixed by reference)
#define NB 8
#define NM 16
#define NC 3
#define NH 128
#define NW 128
#define NG (NH * NW)            // 16384 spatial elems per image
#define NGF (NH * (NW / 2 + 1)) // 8320 rfft2 elems per image
#define NKH 32                  // kept freq rows  (int(128*0.25))
#define NKW 16                  // kept freq cols  (int(65*0.25))
#define NK (NKH * NKW)          // 512 kept coefficients
#define N_PRED_IMG (NB * NM * NC)    // 384 pred images
#define N_IMG (N_PRED_IMG + NB * NC) // 408 images incl. target

#define PT_BLOCKS 384   // point-CRPS blocks (4 cols/thread)
#define FQ_BLOCKS 48    // freq-CRPS blocks

// ws layout:
//  [0,    6144) : double2 pp[384]   point partials {s_mae, s_pair}
//  [6144, 6912) : double2 fp[48]    freq partials
//  [6912, 6916) : unsigned ctr      last-block-done counter
//  [7168, +835584) : float mag[408*512]
#define WS_PP_OFF  0
#define WS_FP_OFF  6144
#define WS_CTR_OFF 6912
#define WS_MAG_OFF 7168

#define PI_F 3.14159265358979323846f

__device__ __forceinline__ float2 cmul(float2 a, float2 b) {
  return make_float2(a.x * b.x - a.y * b.y, a.x * b.y + a.y * b.x);
}

// ---------------------------------------------------------------------------
// Kernel 1: fused pointwise-CRPS (blocks [0,384)) + per-image DFT+|.|
// (blocks [384,792), one image each, staged in LDS; twiddles by register
// recurrence — no LDS twiddle table).
__global__ __launch_bounds__(256) void fused_main_kernel(
    const float* __restrict__ pred,   // (B,M,C,128,128) flat
    const float* __restrict__ tgt,    // (B,C,128,128) flat
    double2* __restrict__ pp,         // [PT_BLOCKS]
    float* __restrict__ mag,          // [408*512]
    unsigned* __restrict__ ctr) {
  __shared__ float4 xs4[32 * 33];     // 32 rows x 132 floats (pad 4) = 16896 B
  __shared__ float2 Yl[NH * NKW];     // row-DFT output [h][kw], 16384 B
  __shared__ float ls1[4], ls2[4];

  const int t = threadIdx.x;
  const int blk = blockIdx.x;

  if (blk < PT_BLOCKS) {
    // ---------------- pointwise CRPS path ----------------
    if (blk == 0 && t == 0) *ctr = 0;   // arm kernel-2's last-block counter
    int i4 = (blk * 256 + t) * 4;
    int b = i4 / (NC * NG);
    int cg = i4 - b * (NC * NG);
    const float* base = pred + (size_t)b * (NM * NC * NG) + cg;
    float4 tv = *(const float4*)&tgt[i4];
    float4 p[NM];
#pragma unroll
    for (int m = 0; m < NM; ++m)
      p[m] = *(const float4*)&base[(size_t)m * (NC * NG)];

    float s1 = 0.f, s2 = 0.f;
#pragma unroll
    for (int m = 0; m < NM; ++m)
      s1 += fabsf(p[m].x - tv.x) + fabsf(p[m].y - tv.y) +
            fabsf(p[m].z - tv.z) + fabsf(p[m].w - tv.w);
#pragma unroll
    for (int m = 0; m < NM; ++m)
#pragma unroll
      for (int j = m + 1; j < NM; ++j)
        s2 += fabsf(p[m].x - p[j].x) + fabsf(p[m].y - p[j].y) +
              fabsf(p[m].z - p[j].z) + fabsf(p[m].w - p[j].w);

    for (int off = 32; off > 0; off >>= 1) {
      s1 += __shfl_down(s1, off);
      s2 += __shfl_down(s2, off);
    }
    if ((t & 63) == 0) { ls1[t >> 6] = s1; ls2[t >> 6] = s2; }
    __syncthreads();
    if (t == 0) {
      double a = 0.0, c = 0.0;
#pragma unroll
      for (int w = 0; w < 4; ++w) { a += (double)ls1[w]; c += (double)ls2[w]; }
      pp[blk] = make_double2(a, c);
    }
    return;
  }

  // ---------------- per-image DFT path ----------------
  const int img = blk - PT_BLOCKS;
  const float* src = (img < N_PRED_IMG)
                         ? pred + (size_t)img * NG
                         : tgt + (size_t)(img - N_PRED_IMG) * NG;
  const float4* src4 = (const float4*)src;

  // Row stage: thread -> (kw = t&15, rows r2 and r2+16 of each 32-row chunk)
  const int kw = t & 15, r2 = t >> 4;
  float sw, cw;
  sincosf(-2.0f * PI_F * (float)kw / 128.0f, &sw, &cw);
  const float2 stepw = make_float2(cw, sw);   // e^{-2pi i kw/128}

  for (int c = 0; c < 4; ++c) {
    // stage 32 rows (4096 floats) coalesced
#pragma unroll
    for (int j = 0; j < 4; ++j) {
      int p = j * 256 + t;                       // float4 idx in chunk
      float4 v = src4[c * 1024 + p];
      xs4[(p >> 5) * 33 + (p & 31)] = v;
    }
    __syncthreads();

    float ax1 = 0.f, ay1 = 0.f, ax2 = 0.f, ay2 = 0.f;
    float2 rt = make_float2(1.f, 0.f);           // e^{-2pi i kw*w/128}, w=0
    const float4* rowA = &xs4[r2 * 33];
    const float4* rowB = &xs4[(r2 + 16) * 33];
#pragma unroll 8
    for (int w4 = 0; w4 < 32; ++w4) {
      float4 a = rowA[w4];
      float4 bb = rowB[w4];
      ax1 = fmaf(a.x, rt.x, ax1); ay1 = fmaf(a.x, rt.y, ay1);
      ax2 = fmaf(bb.x, rt.x, ax2); ay2 = fmaf(bb.x, rt.y, ay2);
      rt = cmul(rt, stepw);
      ax1 = fmaf(a.y, rt.x, ax1); ay1 = fmaf(a.y, rt.y, ay1);
      ax2 = fmaf(bb.y, rt.x, ax2); ay2 = fmaf(bb.y, rt.y, ay2);
      rt = cmul(rt, stepw);
      ax1 = fmaf(a.z, rt.x, ax1); ay1 = fmaf(a.z, rt.y, ay1);
      ax2 = fmaf(bb.z, rt.x, ax2); ay2 = fmaf(bb.z, rt.y, ay2);
      rt = cmul(rt, stepw);
      ax1 = fmaf(a.w, rt.x, ax1); ay1 = fmaf(a.w, rt.y, ay1);
      ax2 = fmaf(bb.w, rt.x, ax2); ay2 = fmaf(bb.w, rt.y, ay2);
      rt = cmul(rt, stepw);
    }
    Yl[(c * 32 + r2) * NKW + kw] = make_float2(ax1, ay1);
    Yl[(c * 32 + r2 + 16) * NKW + kw] = make_float2(ax2, ay2);
    __syncthreads();   // Yl chunk complete / xs4 reusable
  }

  // Column stage: thread -> (kh = t>>3, kw pair {2j, 2j+1}, j = t&7).
  // One float4 LDS read per h yields both complex Y values.
  const int kh = t >> 3, kw2 = (t & 7) * 2;
  float sh, ch;
  sincosf(-2.0f * PI_F * (float)kh / 128.0f, &sh, &ch);
  const float2 steph = make_float2(ch, sh);
  float axA = 0.f, ayA = 0.f, axB = 0.f, ayB = 0.f;
  float2 rt = make_float2(1.f, 0.f);             // e^{-2pi i kh*h/128}, h=0
#pragma unroll 8
  for (int h = 0; h < NH; ++h) {
    float4 y2 = *(const float4*)&Yl[h * NKW + kw2];
    axA = fmaf(y2.x, rt.x, fmaf(-y2.y, rt.y, axA));
    ayA = fmaf(y2.x, rt.y, fmaf(y2.y, rt.x, ayA));
    axB = fmaf(y2.z, rt.x, fmaf(-y2.w, rt.y, axB));
    ayB = fmaf(y2.z, rt.y, fmaf(y2.w, rt.x, ayB));
    rt = cmul(rt, steph);
  }
  float* mo = mag + (size_t)img * NK;
  mo[kh * NKW + kw2] = sqrtf(axA * axA + ayA * ayA);
  mo[kh * NKW + kw2 + 1] = sqrtf(axB * axB + ayB * ayB);
}

// ---------------------------------------------------------------------------
// Kernel 2: frequency CRPS partials + last-block finalize.
__global__ __launch_bounds__(256) void crps_freq_final_kernel(
    const float* __restrict__ mag,    // (408, 512): 384 pred then 24 tgt
    const double2* __restrict__ pp,   // [PT_BLOCKS]
    double2* __restrict__ fp,         // [FQ_BLOCKS]
    unsigned* __restrict__ ctr,
    float* __restrict__ out) {
  const int tid = threadIdx.x;
  int i = blockIdx.x * 256 + tid;
  int b = i / (NC * NK);
  int rem = i - b * (NC * NK);
  const float* pb = mag + (size_t)b * (NM * NC * NK) + rem;
  float t = mag[(size_t)N_PRED_IMG * NK + (size_t)b * (NC * NK) + rem];
  float p[NM];
#pragma unroll
  for (int m = 0; m < NM; ++m) p[m] = pb[(size_t)m * (NC * NK)];
  float s1 = 0.f, s2 = 0.f;
#pragma unroll
  for (int m = 0; m < NM; ++m) s1 += fabsf(p[m] - t);
#pragma unroll
  for (int m = 0; m < NM; ++m)
#pragma unroll
    for (int j = m + 1; j < NM; ++j) s2 += fabsf(p[m] - p[j]);
  for (int off = 32; off > 0; off >>= 1) {
    s1 += __shfl_down(s1, off);
    s2 += __shfl_down(s2, off);
  }
  __shared__ float ls1[4], ls2[4];
  __shared__ int sLast;
  if ((tid & 63) == 0) { ls1[tid >> 6] = s1; ls2[tid >> 6] = s2; }
  __syncthreads();
  if (tid == 0) {
    double a = 0.0, c = 0.0;
#pragma unroll
    for (int w = 0; w < 4; ++w) { a += (double)ls1[w]; c += (double)ls2[w]; }
    fp[blockIdx.x] = make_double2(a, c);
    __threadfence();                      // release fp before counter bump
    unsigned old = atomicAdd(ctr, 1u);
    sLast = (old == FQ_BLOCKS - 1);
  }
  __syncthreads();
  if (!sLast) return;
  __threadfence();                        // acquire other blocks' fp

  // ---- final reduction (one block) ----
  double s1p = 0.0, s2p = 0.0, s1f = 0.0, s2f = 0.0;
  for (int j = tid; j < PT_BLOCKS; j += 256) {
    double2 v = pp[j]; s1p += v.x; s2p += v.y;
  }
  if (tid < FQ_BLOCKS) { double2 v = fp[tid]; s1f += v.x; s2f += v.y; }
  for (int off = 32; off > 0; off >>= 1) {
    s1p += __shfl_down(s1p, off);
    s2p += __shfl_down(s2p, off);
    s1f += __shfl_down(s1f, off);
    s2f += __shfl_down(s2f, off);
  }
  __shared__ double l[4][4];
  if ((tid & 63) == 0) {
    int w = tid >> 6;
    l[w][0] = s1p; l[w][1] = s2p; l[w][2] = s1f; l[w][3] = s2f;
  }
  __syncthreads();
  if (tid == 0) {
    double a0 = 0, a1 = 0, a2 = 0, a3 = 0;
#pragma unroll
    for (int w = 0; w < 4; ++w) {
      a0 += l[w][0]; a1 += l[w][1]; a2 += l[w][2]; a3 += l[w][3];
    }
    const double Bd = NB, Md = NM, Cd = NC, Gd = NG, Gfd = NGF;
    const double eps = 0.05 / Md;
    double term1_p = a0 / (Bd * Cd * Gd * Md);
    double term2_p = (1.0 - eps) * 2.0 * a1 / ((Md - 1.0) * Bd * Md * Cd * Gd);
    double crps_p = term1_p - 0.5 * term2_p;
    double term1_f = a2 / (Bd * Cd * Gfd * Md);
    double term2_f = (1.0 - eps) * 2.0 * a3 / ((Md - 1.0) * Bd * Md * Cd * Gfd);
    double crps_f = term1_f - 0.5 * term2_f;
    out[0] = (float)(crps_p + 0.1 * crps_f);
  }
}

// ---------------------------------------------------------------------------
extern "C" void kernel_launch(void* const* d_in, const int* in_sizes, int n_in,
                              void* d_out, int out_size, void* d_ws, size_t ws_size,
                              hipStream_t stream) {
  (void)in_sizes; (void)n_in; (void)out_size; (void)ws_size;
  const float* tgt = (const float*)d_in[0];   // (8,3,128,128)
  const float* pred = (const float*)d_in[1];  // (8,16,3,128,128)
  float* out = (float*)d_out;

  char* ws = (char*)d_ws;
  double2* pp = (double2*)(ws + WS_PP_OFF);
  double2* fp = (double2*)(ws + WS_FP_OFF);
  unsigned* ctr = (unsigned*)(ws + WS_CTR_OFF);
  float* mag = (float*)(ws + WS_MAG_OFF);

  fused_main_kernel<<<PT_BLOCKS + N_IMG, 256, 0, stream>>>(pred, tgt, pp, mag, ctr);
  crps_freq_final_kernel<<<FQ_BLOCKS, 256, 0, stream>>>(mag, pp, fp, ctr, out);
}